// Round 17
// baseline (120.639 us; speedup 1.0000x reference)
//
#include <hip/hip_runtime.h>
#include <hip/hip_bf16.h>
#include <stdint.h>

#define Rdim 1023
#define BFR  4190208           // 64*64*1023

typedef __bf16 bf16;
typedef __bf16 bf16x8 __attribute__((ext_vector_type(8)));
typedef __bf16 bf16x4 __attribute__((ext_vector_type(4)));
typedef float  f32x4  __attribute__((ext_vector_type(4)));
typedef float  f32x4u __attribute__((ext_vector_type(4), aligned(4)));

__device__ __forceinline__ void async16(const void* g, void* l) {
    __builtin_amdgcn_global_load_lds(
        (const __attribute__((address_space(1))) void*)g,
        (__attribute__((address_space(3))) void*)l, 16, 0, 0);
}

#define BAR()  do { __builtin_amdgcn_s_barrier(); __builtin_amdgcn_sched_barrier(0); } while(0)

// ---------------------------------------------------------------------------
// Prep (r10 verbatim — frozen; measured 56.6 us, 87% of its 49 us floor).
// 2-bit/64B-window swizzle: chunk c of row m stored at (c&~3)|((c&3)^((m>>1)&3)).
// ---------------------------------------------------------------------------
__global__ __launch_bounds__(256) void k_prep(
    const float* __restrict__ x,
    const float* __restrict__ w0, const float* __restrict__ w1,
    const float* __restrict__ w2, const float* __restrict__ w3,
    const float* __restrict__ Dl, const float* __restrict__ Dr,
    const float* __restrict__ El, const float* __restrict__ Er,
    bf16* __restrict__ args, bf16* __restrict__ dpad,
    float* __restrict__ out)
{
    const int blk = blockIdx.x;
    const int t   = threadIdx.x;

    if (blk < 4096) {
        const int b = blk >> 6;
        float wr0[16], wr1[16], wr2[16], wr3[16];
#pragma unroll
        for (int l = 0; l < 16; ++l) {
            wr0[l] = w0[b*16 + l]; wr1[l] = w1[b*16 + l];
            wr2[l] = w2[b*16 + l]; wr3[l] = w3[b*16 + l];
        }
        const float* xb = x + ((size_t)(b*16)*64 + (blk & 63)) * (size_t)Rdim;
        float a0[4] = {}, a1[4] = {}, a2[4] = {}, a3[4] = {};
        if (t < 255) {
#pragma unroll
            for (int l = 0; l < 16; ++l) {
                f32x4u v = *(const f32x4u*)(xb + (size_t)l*(64*(size_t)Rdim) + t*4);
#pragma unroll
                for (int j = 0; j < 4; ++j) {
                    a0[j] += wr0[l]*v[j]; a1[j] += wr1[l]*v[j];
                    a2[j] += wr2[l]*v[j]; a3[j] += wr3[l]*v[j];
                }
            }
        } else {
#pragma unroll
            for (int l = 0; l < 16; ++l) {
                const float* p = xb + (size_t)l*(64*(size_t)Rdim) + 1020;
#pragma unroll
                for (int j = 0; j < 3; ++j) {
                    float v = p[j];
                    a0[j] += wr0[l]*v; a1[j] += wr1[l]*v;
                    a2[j] += wr2[l]*v; a3[j] += wr3[l]*v;
                }
            }
        }
        const int c   = t >> 1;                       // 16B chunk = r/8
        const int S2  = (blk >> 1) & 3;               // 2-bit row swizzle
        const int cw  = (c & ~3) | ((c & 3) ^ S2);
        const int off = (cw << 3) + ((t & 1) << 2);
        bf16x4 s0, s1, s2, s3;
#pragma unroll
        for (int j = 0; j < 4; ++j) {
            s0[j] = (bf16)a0[j]; s1[j] = (bf16)a1[j];
            s2[j] = (bf16)a2[j]; s3[j] = (bf16)a3[j];
        }
        *(bf16x4*)(args +            (size_t)blk*1024 + off) = s0;
        *(bf16x4*)(args + 4194304 +  (size_t)blk*1024 + off) = s1;
        bf16* c12 = args + 8388608 + (size_t)blk*2048;
        *(bf16x4*)(c12 + off)        = s2;
        *(bf16x4*)(c12 + 1024 + off) = s3;
    } else if (blk < 6144) {
        const int id = (blk - 4096)*256 + t;
        const float* src; int n, c, K; size_t base;
        if (id < 262144) {
            const int m2  = id >> 17;
            src = m2 ? Dr : Dl;
            const int rem = id & 131071;
            n = rem >> 7; c = rem & 127; K = 1024;
            base = m2 ? 1048576u : 0u;
        } else {
            const int rem = id - 262144;
            n = rem >> 8; c = rem & 255; K = 2048;
            base = 2097152u;
            src = (c < 128) ? El : Er;
        }
        const int cl = c & 127;
        float v[8] = {};
        if (n < Rdim) {
            const float* sp = src + (size_t)n*Rdim + cl*8;
            if (cl < 127) {
                f32x4u u0 = *(const f32x4u*)sp;
                f32x4u u1 = *(const f32x4u*)(sp + 4);
#pragma unroll
                for (int j = 0; j < 4; ++j) { v[j] = u0[j]; v[4+j] = u1[j]; }
            } else {
                f32x4u u0 = *(const f32x4u*)sp;
#pragma unroll
                for (int j = 0; j < 4; ++j) v[j] = u0[j];
                v[4] = sp[4]; v[5] = sp[5]; v[6] = sp[6];
            }
        }
        const int swc = (c & ~3) | ((c & 3) ^ ((n >> 1) & 3));
        bf16x8 s;
#pragma unroll
        for (int j = 0; j < 8; ++j) s[j] = (bf16)v[j];
        *(bf16x8*)(dpad + base + (size_t)n*K + swc*8) = s;
    } else {
        const int k = t >> 6, b2 = t & 63;
        const float* w = (k==0) ? w0 : (k==1) ? w1 : (k==2) ? w2 : w3;
        float s = 0.f, mx = -1e30f;
#pragma unroll
        for (int l = 0; l < 16; ++l) {
            float p = w[b2*16 + l];
            s += p * logf(p + 1e-12f);
            mx = fmaxf(mx, p);
        }
        out[3*(size_t)BFR +       k*64 + b2] = -s / logf(16.f);
        out[3*(size_t)BFR + 256 + k*64 + b2] = mx;
    }
}

// ---------------------------------------------------------------------------
// GEMM — r10 template verbatim; ALL jobs now 256x256 tiles (r15-probe
// insight: GEMM is L3-BW-bound on staged bytes — 320 MB @ ~7.8 TB/s = 41 us.
// cons at 128x256 re-staged each B panel 32x; at 256x256 only 16x.
// Total staged 320 -> 224 MB). Grid 192 blocks (8 cons + 8 car + 8 cdr
// per XCD, cons-first — cons blocks are 2 work-units, co-resident from t=0).
// BK=32, triple-buffered 96 KiB LDS, 1 barrier/kt, counted vmcnt(4).
// ---------------------------------------------------------------------------
template<int NKT, bool CONS>
__device__ __forceinline__ void gemm_t(
    const bf16* __restrict__ Ab, const bf16* __restrict__ Bb,
    const float* __restrict__ rf, const float* __restrict__ rr,
    float* __restrict__ outp, char* lds, int mt, int nt)
{
    constexpr int AstB = CONS ? 4096 : 2048;   // row stride bytes (A and B)
    constexpr int MI   = 8;                    // A frags per wave (BM=256)
    constexpr int ABUF = 16384;                // bytes per A buffer

    const int tid  = threadIdx.x;
    const int wave = tid >> 6, lane = tid & 63;
    const int wm   = wave >> 2, wn = wave & 3; // 2M x 4N
    const int lr   = lane & 15, lk = lane >> 4;
    const int cc16 = (lk ^ ((lr >> 1) & 3)) << 4;

    const char* AgT = (const char*)Ab + (size_t)(mt*256 + (tid>>2))*AstB + (tid&3)*16;
    const char* BgT = (const char*)Bb + (size_t)(nt*256 + (tid>>2))*AstB + (tid&3)*16;

    f32x4 acc[MI][4] = {};
    bf16x8 af[MI], bfr[4];

#define STG(bufidx, kt) do {                                                  \
    char* _a = lds + (bufidx)*ABUF + wave*1024;                               \
    char* _b = lds + 49152 + (bufidx)*16384 + wave*1024;                      \
    const size_t _ko = (size_t)(kt)*64;                                       \
    _Pragma("unroll") for (int i = 0; i < 2; ++i)                             \
        async16(AgT + (size_t)(i*128)*AstB + _ko, _a + i*8192);               \
    _Pragma("unroll") for (int i = 0; i < 2; ++i)                             \
        async16(BgT + (size_t)(i*128)*AstB + _ko, _b + i*8192);               \
} while(0)

    // prologue: kt0 -> buf0, kt1 -> buf1; wait kt0 landed (kt1's 4 remain)
    STG(0, 0); STG(1, 1);
    asm volatile("s_waitcnt vmcnt(4)" ::: "memory");
    BAR();

    int cb = 0;
    for (int kt = 0; kt < NKT; ++kt) {
        char* cA = lds + cb*ABUF;
        char* cB = lds + 49152 + cb*16384;
        int sb = cb + 2; if (sb >= 3) sb -= 3;
        const bool st = (kt + 2 < NKT);
#pragma unroll
        for (int mi = 0; mi < MI; ++mi)
            af[mi] = *(const bf16x8*)(cA + (wm*128 + mi*16 + lr)*64 + cc16);
#pragma unroll
        for (int j = 0; j < 4; ++j)
            bfr[j] = *(const bf16x8*)(cB + (wn*64 + j*16 + lr)*64 + cc16);
        if (st) STG(sb, kt+2);
        __builtin_amdgcn_s_setprio(1);
#pragma unroll
        for (int mi = 0; mi < MI; ++mi)
#pragma unroll
        for (int j = 0; j < 4; ++j)
            acc[mi][j] = __builtin_amdgcn_mfma_f32_16x16x32_bf16(
                af[mi], bfr[j], acc[mi][j], 0, 0, 0);
        __builtin_amdgcn_s_setprio(0);
        if (st)                { asm volatile("s_waitcnt vmcnt(4)" ::: "memory"); }
        else if (kt == NKT-2)  { asm volatile("s_waitcnt vmcnt(0)" ::: "memory"); }
        BAR();
        cb = cb + 1; if (cb == 3) cb = 0;
    }
#undef STG

    // epilogue: 16x16 C/D: col = lane&15, row = (lane>>4)*4 + q
#pragma unroll
    for (int mi = 0; mi < MI; ++mi) {
        const int gm0 = mt*256 + wm*128 + mi*16 + lk*4;
#pragma unroll
        for (int j = 0; j < 4; ++j) {
            const int gn = nt*256 + wn*64 + j*16 + lr;
            if (gn < Rdim) {
                const float rv = CONS ? rr[gn] : 0.f;
#pragma unroll
                for (int q = 0; q < 4; ++q) {
                    float v = acc[mi][j][q];
                    if (CONS) v += rf[gm0 + q] * rv;
                    outp[(size_t)(gm0 + q)*Rdim + gn] = v;
                }
            }
        }
    }
}

// 192 blocks: per XCD 8 cons (256x256, K=2048, FIRST — 2 work-units each)
// + 8 car + 8 cdr (256x256, K=1024).
__global__ __launch_bounds__(512, 1) void k_gemm(
    const bf16* __restrict__ args, const bf16* __restrict__ dpad,
    const float* __restrict__ root_filler, const float* __restrict__ root_role,
    float* __restrict__ out)
{
    __shared__ char lds[98304];       // 96 KiB
    const int bid = blockIdx.x;
    const int xcd = bid & 7, idx = bid >> 3;   // idx 0..23

    if (idx < 8) {
        const int tile = xcd*8 + idx;          // 0..63: mt 0..15, nt 0..3
        gemm_t<64, true >(args + 8388608, dpad + 2097152,
            root_filler, root_role, out + 2*(size_t)BFR, lds, tile >> 2, tile & 3);
    } else if (idx < 16) {
        const int tile = xcd*8 + idx - 8;      // 0..63: mt 0..15, nt 0..3
        gemm_t<32, false>(args, dpad,
            root_filler, root_role, out, lds, tile >> 2, tile & 3);
    } else {
        const int tile = xcd*8 + idx - 16;
        gemm_t<32, false>(args + 4194304, dpad + 1048576,
            root_filler, root_role, out + (size_t)BFR, lds, tile >> 2, tile & 3);
    }
}

// ---------------------------------------------------------------------------
extern "C" void kernel_launch(void* const* d_in, const int* in_sizes, int n_in,
                              void* d_out, int out_size, void* d_ws, size_t ws_size,
                              hipStream_t stream)
{
    const float* x           = (const float*)d_in[0];
    const float* car_w       = (const float*)d_in[1];
    const float* cdr_w       = (const float*)d_in[2];
    const float* cons1_w     = (const float*)d_in[3];
    const float* cons2_w     = (const float*)d_in[4];
    const float* root_filler = (const float*)d_in[5];
    const float* Dl          = (const float*)d_in[6];
    const float* Dr          = (const float*)d_in[7];
    const float* El          = (const float*)d_in[8];
    const float* Er          = (const float*)d_in[9];
    const float* root_role   = (const float*)d_in[10];
    float* out = (float*)d_out;

    bf16* args = (bf16*)d_ws;                 // 33.5 MB
    bf16* dpad = args + 16777216;             //  8.4 MB

    k_prep<<<dim3(6145), dim3(256), 0, stream>>>(
        x, car_w, cdr_w, cons1_w, cons2_w, Dl, Dr, El, Er, args, dpad, out);
    k_gemm<<<dim3(192),  dim3(512), 0, stream>>>(
        args, dpad, root_filler, root_role, out);
}

// Round 18
// 102.687 us; speedup vs baseline: 1.1748x; 1.1748x over previous
//
#include <hip/hip_runtime.h>
#include <hip/hip_bf16.h>
#include <hip/hip_fp8.h>
#include <stdint.h>

#define Rdim 1023
#define BFR  4190208           // 64*64*1023

typedef float  f32x4  __attribute__((ext_vector_type(4)));
typedef float  f32x4u __attribute__((ext_vector_type(4), aligned(4)));

__device__ __forceinline__ void async16(const void* g, void* l) {
    __builtin_amdgcn_global_load_lds(
        (const __attribute__((address_space(1))) void*)g,
        (__attribute__((address_space(3))) void*)l, 16, 0, 0);
}

#define BAR()  do { __builtin_amdgcn_s_barrier(); __builtin_amdgcn_sched_barrier(0); } while(0)

__device__ __forceinline__ uint32_t f2fp8(float f) {
    __hip_fp8_e4m3 v(f);
    return (uint32_t)v.__x;
}
__device__ __forceinline__ uint32_t pack4(const float* a, float s) {
    return f2fp8(s*a[0]) | (f2fp8(s*a[1])<<8) | (f2fp8(s*a[2])<<16) | (f2fp8(s*a[3])<<24);
}

// ---------------------------------------------------------------------------
// Prep -> fp8 e4m3. args unscaled; D/E scaled x16 (keeps N(0,0.05) entries
// out of denormal range; epilogue multiplies by 1/16). Swizzle for 64B-row
// fp8: 16B chunk c=(r>>4)&3 of row m stored at c^((m>>1)&3) within its 64B
// window -> GEMM staging stays a LINEAR copy; ds_read_b64 banks 2-way=free.
// blocks [0,1024): dpad8; [1024,5120): args8 (m=blk-1024); 5120: stats.
// ---------------------------------------------------------------------------
__global__ __launch_bounds__(256) void k_prep(
    const float* __restrict__ x,
    const float* __restrict__ w0, const float* __restrict__ w1,
    const float* __restrict__ w2, const float* __restrict__ w3,
    const float* __restrict__ Dl, const float* __restrict__ Dr,
    const float* __restrict__ El, const float* __restrict__ Er,
    uint8_t* __restrict__ args8, uint8_t* __restrict__ dpad8,
    float* __restrict__ out)
{
    const int blk = blockIdx.x;
    const int t   = threadIdx.x;

    if (blk < 1024) {
        // ---- dpad8: one 16B chunk (16 fp8) per thread ----
        const int id = blk*256 + t;              // 0..262143
        const float* src; int n, c16, r0; size_t dst; int stride;
        if (id < 131072) {
            const int mat = id >> 16;            // 0=Dl 1=Dr
            src = mat ? Dr : Dl;
            const int rem = id & 65535;
            n = rem >> 6; c16 = rem & 63; r0 = c16*16; stride = 1024;
            dst = (mat ? 1048576u : 0u);
        } else {
            const int rem = id - 131072;
            n = rem >> 7; c16 = rem & 127;
            r0 = (c16 & 63)*16; stride = 2048;
            src = (c16 < 64) ? El : Er;
            dst = 2097152u;
        }
        const int pos = ((c16 >> 2) << 6) + (((c16 & 3) ^ ((n >> 1) & 3)) << 4);
        float v[16] = {};
        if (n < Rdim) {
            const float* sp = src + (size_t)n*Rdim + r0;
            if (r0 <= Rdim - 16) {
#pragma unroll
                for (int j = 0; j < 4; ++j) {
                    f32x4u u = *(const f32x4u*)(sp + j*4);
#pragma unroll
                    for (int q = 0; q < 4; ++q) v[j*4+q] = u[q];
                }
            } else {                              // r0 = 1008: 15 valid
#pragma unroll
                for (int j = 0; j < 3; ++j) {
                    f32x4u u = *(const f32x4u*)(sp + j*4);
#pragma unroll
                    for (int q = 0; q < 4; ++q) v[j*4+q] = u[q];
                }
                v[12] = sp[12]; v[13] = sp[13]; v[14] = sp[14];  // r=1023 pad
            }
        }
        uint32_t w[4];
#pragma unroll
        for (int j = 0; j < 4; ++j) w[j] = pack4(v + j*4, 16.f);
        *(uint4*)(dpad8 + dst + (size_t)n*stride + pos) =
            make_uint4(w[0], w[1], w[2], w[3]);
    } else if (blk < 5120) {
        // ---- args8: m = blk - 1024, thread t owns r = t*4..t*4+3 ----
        const int m = blk - 1024;
        const int b = m >> 6;
        float wr0[16], wr1[16], wr2[16], wr3[16];
#pragma unroll
        for (int l = 0; l < 16; ++l) {
            wr0[l] = w0[b*16 + l]; wr1[l] = w1[b*16 + l];
            wr2[l] = w2[b*16 + l]; wr3[l] = w3[b*16 + l];
        }
        const float* xb = x + ((size_t)(b*16)*64 + (m & 63)) * (size_t)Rdim;
        float a0[4] = {}, a1[4] = {}, a2[4] = {}, a3[4] = {};
        if (t < 255) {
#pragma unroll
            for (int l = 0; l < 16; ++l) {
                f32x4u v = *(const f32x4u*)(xb + (size_t)l*(64*(size_t)Rdim) + t*4);
#pragma unroll
                for (int j = 0; j < 4; ++j) {
                    a0[j] += wr0[l]*v[j]; a1[j] += wr1[l]*v[j];
                    a2[j] += wr2[l]*v[j]; a3[j] += wr3[l]*v[j];
                }
            }
        } else {
#pragma unroll
            for (int l = 0; l < 16; ++l) {
                const float* p = xb + (size_t)l*(64*(size_t)Rdim) + 1020;
#pragma unroll
                for (int j = 0; j < 3; ++j) {
                    float v = p[j];
                    a0[j] += wr0[l]*v; a1[j] += wr1[l]*v;
                    a2[j] += wr2[l]*v; a3[j] += wr3[l]*v;
                }
            }
        }
        const int r0  = t*4;
        const int S2  = (m >> 1) & 3;
        const int pos = ((r0 >> 6) << 6) + ((((r0 >> 4) & 3) ^ S2) << 4) + (r0 & 15);
        *(uint32_t*)(args8 +            (size_t)m*1024 + pos) = pack4(a0, 1.f);
        *(uint32_t*)(args8 + 4194304 +  (size_t)m*1024 + pos) = pack4(a1, 1.f);
        uint8_t* c12 = args8 + 8388608 + (size_t)m*2048;
        *(uint32_t*)(c12 + pos)        = pack4(a2, 1.f);
        *(uint32_t*)(c12 + 1024 + pos) = pack4(a3, 1.f);
    } else {
        const int k = t >> 6, b2 = t & 63;
        const float* w = (k==0) ? w0 : (k==1) ? w1 : (k==2) ? w2 : w3;
        float s = 0.f, mx = -1e30f;
#pragma unroll
        for (int l = 0; l < 16; ++l) {
            float p = w[b2*16 + l];
            s += p * logf(p + 1e-12f);
            mx = fmaxf(mx, p);
        }
        out[3*(size_t)BFR +       k*64 + b2] = -s / logf(16.f);
        out[3*(size_t)BFR + 256 + k*64 + b2] = mx;
    }
}

// ---------------------------------------------------------------------------
// GEMM — r10 skeleton verbatim, fp8 e4m3 operands (16x16x32_fp8_fp8, bf16
// rate -> same MFMA floor; all staging/LDS/latency costs halve). BK=64 fp8
// (64 B/row/kt — same bytes as r10's BK=32 bf16, same LDS map, same vmcnt).
// car/cdr BM=256 K=1024 (NKT=16), cons BM=128 K=2048 (NKT=32).
// 256 blocks (16 cons + 8 car + 8 cdr per XCD), 96 KiB LDS, 1 barrier/kt.
// Epilogue x(1/16) undoes the D/E scale.
// ---------------------------------------------------------------------------
template<int BM, int NKT, int VM, bool CONS>
__device__ __forceinline__ void gemm_t(
    const uint8_t* __restrict__ Ab, const uint8_t* __restrict__ Bb,
    const float* __restrict__ rf, const float* __restrict__ rr,
    float* __restrict__ outp, char* lds, int mt, int nt)
{
    constexpr int AstB = CONS ? 2048 : 1024;   // row stride bytes (A and B)
    constexpr int MI   = BM / 32;              // A frags per wave
    constexpr int ABUF = BM * 64;              // bytes per A buffer

    const int tid  = threadIdx.x;
    const int wave = tid >> 6, lane = tid & 63;
    const int wm   = wave >> 2, wn = wave & 3; // 2M x 4N
    const int lr   = lane & 15, lk = lane >> 4;
    const int sw   = (lr >> 1) & 3;
    // ks-chunk byte offsets within a 64B row (b64 reads, banks 2-way = free)
    const int cb0 = ((((lk >> 1)    ) ^ sw) << 4) + ((lk & 1) << 3);
    const int cb1 = (((2 + (lk >> 1)) ^ sw) << 4) + ((lk & 1) << 3);

    const uint8_t* AgT = Ab + (size_t)(mt*BM  + (tid>>2))*AstB + (tid&3)*16;
    const uint8_t* BgT = Bb + (size_t)(nt*256 + (tid>>2))*AstB + (tid&3)*16;

    f32x4 acc[MI][4] = {};
    long af[MI][2], bfr[4][2];

#define STG(bufidx, kt) do {                                                  \
    char* _a = lds + (bufidx)*ABUF + wave*1024;                               \
    char* _b = lds + 49152 + (bufidx)*16384 + wave*1024;                      \
    const size_t _ko = (size_t)(kt)*64;                                       \
    _Pragma("unroll") for (int i = 0; i < BM/128; ++i)                        \
        async16(AgT + (size_t)(i*128)*AstB + _ko, _a + i*8192);               \
    _Pragma("unroll") for (int i = 0; i < 2; ++i)                             \
        async16(BgT + (size_t)(i*128)*AstB + _ko, _b + i*8192);               \
} while(0)

    STG(0, 0); STG(1, 1);
    asm volatile("s_waitcnt vmcnt(%0)" :: "n"(VM) : "memory");
    BAR();

    int cb = 0;
    for (int kt = 0; kt < NKT; ++kt) {
        char* cA = lds + cb*ABUF;
        char* cB = lds + 49152 + cb*16384;
        int sb = cb + 2; if (sb >= 3) sb -= 3;
        const bool st = (kt + 2 < NKT);
#pragma unroll
        for (int mi = 0; mi < MI; ++mi) {
            const char* rp = cA + (wm*(BM/2) + mi*16 + lr)*64;
            af[mi][0] = *(const long*)(rp + cb0);
            af[mi][1] = *(const long*)(rp + cb1);
        }
#pragma unroll
        for (int j = 0; j < 4; ++j) {
            const char* rp = cB + (wn*64 + j*16 + lr)*64;
            bfr[j][0] = *(const long*)(rp + cb0);
            bfr[j][1] = *(const long*)(rp + cb1);
        }
        if (st) STG(sb, kt+2);
        __builtin_amdgcn_s_setprio(1);
#pragma unroll
        for (int ks = 0; ks < 2; ++ks)
#pragma unroll
        for (int mi = 0; mi < MI; ++mi)
#pragma unroll
        for (int j = 0; j < 4; ++j)
            acc[mi][j] = __builtin_amdgcn_mfma_f32_16x16x32_fp8_fp8(
                af[mi][ks], bfr[j][ks], acc[mi][j], 0, 0, 0);
        __builtin_amdgcn_s_setprio(0);
        if (st)                { asm volatile("s_waitcnt vmcnt(%0)" :: "n"(VM) : "memory"); }
        else if (kt == NKT-2)  { asm volatile("s_waitcnt vmcnt(0)" ::: "memory"); }
        BAR();
        cb = cb + 1; if (cb == 3) cb = 0;
    }
#undef STG

    // epilogue: 16x16 C/D: col = lane&15, row = (lane>>4)*4 + q; undo x16
#pragma unroll
    for (int mi = 0; mi < MI; ++mi) {
        const int gm0 = mt*BM + wm*(BM/2) + mi*16 + lk*4;
#pragma unroll
        for (int j = 0; j < 4; ++j) {
            const int gn = nt*256 + wn*64 + j*16 + lr;
            if (gn < Rdim) {
                const float rv = CONS ? rr[gn] : 0.f;
#pragma unroll
                for (int q = 0; q < 4; ++q) {
                    float v = acc[mi][j][q] * 0.0625f;
                    if (CONS) v += rf[gm0 + q] * rv;
                    outp[(size_t)(gm0 + q)*Rdim + gn] = v;
                }
            }
        }
    }
}

// 256 blocks: per XCD 16 cons (128x256, K=2048, FIRST) + 8 car + 8 cdr
// (256x256, K=1024) — every block exactly one work unit (r10 packing).
__global__ __launch_bounds__(512, 1) void k_gemm(
    const uint8_t* __restrict__ args8, const uint8_t* __restrict__ dpad8,
    const float* __restrict__ root_filler, const float* __restrict__ root_role,
    float* __restrict__ out)
{
    __shared__ char lds[98304];       // 96 KiB
    const int bid = blockIdx.x;
    const int xcd = bid & 7, idx = bid >> 3;   // idx 0..31

    if (idx < 16) {
        const int tile = xcd*16 + idx;         // 0..127: mt 0..31, nt 0..3
        gemm_t<128, 32, 3, true >(args8 + 8388608, dpad8 + 2097152,
            root_filler, root_role, out + 2*(size_t)BFR, lds, tile >> 2, tile & 3);
    } else if (idx < 24) {
        const int tile = xcd*8 + idx - 16;     // 0..63: mt 0..15, nt 0..3
        gemm_t<256, 16, 4, false>(args8, dpad8,
            root_filler, root_role, out, lds, tile >> 2, tile & 3);
    } else {
        const int tile = xcd*8 + idx - 24;
        gemm_t<256, 16, 4, false>(args8 + 4194304, dpad8 + 1048576,
            root_filler, root_role, out + (size_t)BFR, lds, tile >> 2, tile & 3);
    }
}

// ---------------------------------------------------------------------------
extern "C" void kernel_launch(void* const* d_in, const int* in_sizes, int n_in,
                              void* d_out, int out_size, void* d_ws, size_t ws_size,
                              hipStream_t stream)
{
    const float* x           = (const float*)d_in[0];
    const float* car_w       = (const float*)d_in[1];
    const float* cdr_w       = (const float*)d_in[2];
    const float* cons1_w     = (const float*)d_in[3];
    const float* cons2_w     = (const float*)d_in[4];
    const float* root_filler = (const float*)d_in[5];
    const float* Dl          = (const float*)d_in[6];
    const float* Dr          = (const float*)d_in[7];
    const float* El          = (const float*)d_in[8];
    const float* Er          = (const float*)d_in[9];
    const float* root_role   = (const float*)d_in[10];
    float* out = (float*)d_out;

    uint8_t* args8 = (uint8_t*)d_ws;              // 16.8 MB
    uint8_t* dpad8 = args8 + 16777216;            //  4.2 MB

    k_prep<<<dim3(5121), dim3(256), 0, stream>>>(
        x, car_w, cdr_w, cons1_w, cons2_w, Dl, Dr, El, Er, args8, dpad8, out);
    k_gemm<<<dim3(256),  dim3(512), 0, stream>>>(
        args8, dpad8, root_filler, root_role, out);
}